// Round 20
// baseline (138.333 us; speedup 1.0000x reference)
//
#include <hip/hip_runtime.h>
#include <hip/hip_bf16.h>

#define DH    32          // d_head
#define NH    8
#define NPTS  4
#define CDIM  256
#define HW    16384       // H*W = 128*128
#define HDIM  128

typedef __attribute__((ext_vector_type(8))) short bf16x8;
typedef __attribute__((ext_vector_type(4))) float f32x4;
typedef __attribute__((ext_vector_type(2))) float f32x2;
typedef __attribute__((ext_vector_type(8))) unsigned short u16x8;

__device__ __forceinline__ unsigned short f2bf(float f) {
  unsigned u = __float_as_uint(f);
  u += 0x7FFFu + ((u >> 16) & 1u);          // round-to-nearest-even
  return (unsigned short)(u >> 16);
}
__device__ __forceinline__ float bf2f(unsigned short s) {
  return __uint_as_float(((unsigned)s) << 16);
}
// hardware RNE cast (pairs compile to v_cvt_pk_bf16_f32)
__device__ __forceinline__ unsigned short hwbf(float f) {
  __hip_bfloat16 h = __float2bfloat16(f);
  return __builtin_bit_cast(unsigned short, h);
}
// async global->LDS DMA, 16B per lane; lds dst must be wave-uniform
__device__ __forceinline__ void gload16(const void* g, void* l) {
  __builtin_amdgcn_global_load_lds(
      (const __attribute__((address_space(1))) void*)g,
      (__attribute__((address_space(3))) void*)l, 16, 0, 0);
}

// ---------------------------------------------------------------------------
// One-shot weight prep: f32 [k][col] (256x256) -> bf16 transposed [col][k].
// ---------------------------------------------------------------------------
__global__ __launch_bounds__(256) void prep_k(
    const float* __restrict__ W0, const float* __restrict__ W1,
    unsigned short* __restrict__ T0, unsigned short* __restrict__ T1) {
  __shared__ unsigned short tile[64][68];
  const float* W = blockIdx.z ? W1 : W0;
  unsigned short* T = blockIdx.z ? T1 : T0;
  const int r0 = blockIdx.x * 64, c0 = blockIdx.y * 64;
  const int t = threadIdx.x;
  #pragma unroll
  for (int i = 0; i < 4; ++i) {
    int f = t + i * 256;                     // 1024 float4
    int r = f >> 4, c4 = (f & 15) << 2;
    float4 v = *(const float4*)(W + (size_t)(r0 + r) * CDIM + c0 + c4);
    ushort4 s;
    s.x = f2bf(v.x); s.y = f2bf(v.y); s.z = f2bf(v.z); s.w = f2bf(v.w);
    *(ushort4*)&tile[r][c4] = s;
  }
  __syncthreads();
  #pragma unroll
  for (int i = 0; i < 4; ++i) {
    int f = t + i * 256;
    int c = f >> 4, r4 = (f & 15) << 2;
    ushort4 o;
    o.x = tile[r4 + 0][c]; o.y = tile[r4 + 1][c];
    o.z = tile[r4 + 2][c]; o.w = tile[r4 + 3][c];
    *(ushort4*)(T + (size_t)(c0 + c) * CDIM + r0 + r4) = o;
  }
}

// ---------------------------------------------------------------------------
// One-shot offset/attn weight prep: split hi/lo bf16, transposed [col][k].
// ---------------------------------------------------------------------------
__global__ __launch_bounds__(256) void prepw_k(
    const float* __restrict__ Woff, const float* __restrict__ Wattn,
    unsigned short* __restrict__ Whi, unsigned short* __restrict__ Wlo) {
  const int c = blockIdx.x, k = threadIdx.x;
  float x = (c < 64) ? Woff[(size_t)k * 64 + c] : Wattn[(size_t)k * 32 + (c - 64)];
  unsigned short h = f2bf(x);
  Whi[(size_t)c * 256 + k] = h;
  Wlo[(size_t)c * 256 + k] = f2bf(x - bf2f(h));
}

// ---------------------------------------------------------------------------
// GEMM, full-width MT x 256 tile (A read once from HBM). MT=64 for the f32
// value GEMM (48KB LDS -> 3 blocks/CU, +50% waves vs MT=128's 2) and MT=128
// for the bf16 mid GEMM. 4 waves: wave w owns rows (w>>1)*(MT/2), cols
// (w&1)*128; acc[MT/32][8]. BK=32, double-buffered LDS via global_load_lds,
// counted-vmcnt schedule (next tile's loads stay in flight across barriers).
// A-f32 XOR-swizzled (pre-swizzled global src + swizzled ds_read); bf16 A
// and B linear (bank-uniform b128 reads).
// ---------------------------------------------------------------------------
template<bool ABF16, int EPI, int MT>
__global__ __launch_bounds__(256) void gemm_k(
    const void* __restrict__ Ap, const unsigned short* __restrict__ Bt,
    const float* __restrict__ bias, void* __restrict__ Cp, int Mrows) {
  constexpr int MREP = MT / 32;                    // fragment rows per wave
  constexpr int ABUF = ABF16 ? MT * 64 : MT * 128; // bytes per A buffer
  constexpr int NCHA = ABF16 ? (MT / 64) : (MT / 32); // A chunks per wave
  constexpr int VM = NCHA + 4;                     // next-tile loads in flight
  __shared__ char lds[2 * ABUF + 32768];
  char* Abase = lds;
  char* Bbase = lds + 2 * ABUF;                    // [2][256col][64B]
  const int mt = blockIdx.x;
  const int t = threadIdx.x;
  const int lane = t & 63, w = t >> 6;
  const int wr = w >> 1, wcol = w & 1;
  const int l15 = lane & 15, l4 = lane >> 4;
  const char* Ag = (const char*)Ap;

  f32x4 acc[MREP][8] = {};

  auto stage = [&](int kk, int s) {
    if (!ABF16) {
      const int lrow = lane >> 3;
      const int lkb = ((lane & 7) ^ lrow) << 4;    // XOR pre-swizzle
      #pragma unroll
      for (int i = 0; i < NCHA; ++i) {
        int chunk = w * NCHA + i;
        int row = chunk * 8 + lrow;
        const char* src = Ag + ((size_t)(mt * MT + row) * CDIM + kk * 32) * 4 + lkb;
        gload16(src, Abase + s * ABUF + chunk * 1024);
      }
    } else {
      const int lrow = lane >> 2;
      const int lkb = (lane & 3) << 4;
      #pragma unroll
      for (int i = 0; i < NCHA; ++i) {
        int chunk = w * NCHA + i;
        int row = chunk * 16 + lrow;
        const char* src = Ag + ((size_t)kk * Mrows + mt * MT + row) * 64 + lkb;
        gload16(src, Abase + s * ABUF + chunk * 1024);
      }
    }
    const int lcol = lane >> 2;
    const int lkb2 = (lane & 3) << 4;
    #pragma unroll
    for (int i = 0; i < 4; ++i) {
      int chunk = w * 4 + i;
      int col = chunk * 16 + lcol;
      const char* src = (const char*)Bt + ((size_t)col * CDIM + kk * 32) * 2 + lkb2;
      gload16(src, Bbase + s * 16384 + chunk * 1024);
    }
  };

  stage(0, 0);
  #pragma unroll
  for (int kk = 0; kk < 8; ++kk) {
    const int s = kk & 1;
    if (kk < 7) {
      stage(kk + 1, s ^ 1);
      asm volatile("s_waitcnt vmcnt(%0)" :: "i"(VM) : "memory");
    } else {
      asm volatile("s_waitcnt vmcnt(0)" ::: "memory");
    }
    __builtin_amdgcn_s_barrier();
    bf16x8 a[MREP];
    bf16x8 bb[8];
    if (!ABF16) {
      const int sw = (l15 & 7) << 4;
      #pragma unroll
      for (int m = 0; m < MREP; ++m) {
        const char* arow = Abase + s * ABUF + (wr * (MT / 2) + m * 16 + l15) * 128;
        f32x4 v0 = *(const f32x4*)(arow + ((l4 * 32) ^ sw));
        f32x4 v1 = *(const f32x4*)(arow + ((l4 * 32 + 16) ^ sw));
        #pragma unroll
        for (int i = 0; i < 4; ++i) {
          a[m][i]     = (short)hwbf(v0[i]);
          a[m][4 + i] = (short)hwbf(v1[i]);
        }
      }
    } else {
      #pragma unroll
      for (int m = 0; m < MREP; ++m)
        a[m] = *(const bf16x8*)(Abase + s * ABUF +
                                (wr * (MT / 2) + m * 16 + l15) * 64 + l4 * 16);
    }
    #pragma unroll
    for (int n = 0; n < 8; ++n)
      bb[n] = *(const bf16x8*)(Bbase + s * 16384 +
                               (wcol * 128 + n * 16 + l15) * 64 + l4 * 16);
    #pragma unroll
    for (int m = 0; m < MREP; ++m)
      #pragma unroll
      for (int n = 0; n < 8; ++n)
        acc[m][n] = __builtin_amdgcn_mfma_f32_16x16x32_bf16(a[m], bb[n], acc[m][n], 0, 0, 0);
    asm volatile("s_waitcnt lgkmcnt(0)" ::: "memory");
    __builtin_amdgcn_s_barrier();        // buffer-overwrite protection
  }

  #pragma unroll
  for (int m = 0; m < MREP; ++m) {
    #pragma unroll
    for (int n = 0; n < 8; ++n) {
      #pragma unroll
      for (int r = 0; r < 4; ++r) {
        int R = mt * MT + wr * (MT / 2) + m * 16 + l4 * 4 + r;
        int Cg = wcol * 128 + n * 16 + l15;
        float v = acc[m][n][r] + bias[Cg];
        if (EPI == 0) {
          int b2 = R >> 14, ntok = R & (HW - 1);
          int h = Cg >> 5, c = Cg & 31;
          ((unsigned short*)Cp)[((size_t)(b2 * NH + h) * HW + ntok) * DH + c] = hwbf(v);
        } else {
          ((float*)Cp)[(size_t)R * CDIM + Cg] = v;
        }
      }
    }
  }
}

// ---------------------------------------------------------------------------
// Offsets + attention (R16-best): barrier-free K-loop + 2-deep A prefetch.
// Weights (hi/lo bf16, [col][k]) in LDS once (54KB); A (query f32) read
// straight from global into fragments, split hi/lo in-register.
// 1-D grid, cy = bid&1 (col-half pairs dispatch-adjacent -> L2 pairing).
// Block: 512 thr (8 waves x 32 rows).
// ---------------------------------------------------------------------------
__global__ __launch_bounds__(512) void offattn_k(
    const float* __restrict__ query, const float* __restrict__ refp,
    const unsigned short* __restrict__ Whi, const unsigned short* __restrict__ Wlo,
    const float* __restrict__ boff, const float* __restrict__ battn,
    float* __restrict__ loc, float* __restrict__ attnw, int Mrows) {
  __shared__ unsigned short Bh[8][48][36], Bl[8][48][36];   // 54 KB
  const int t = threadIdx.x;
  const int lane = t & 63, w = t >> 6;
  const int l15 = lane & 15, l4 = lane >> 4;
  const int cy = blockIdx.x & 1;             // col-half: cols cy*48..cy*48+47
  const int row0 = (blockIdx.x >> 1) * 256 + w * 32;

  #pragma unroll
  for (int i = 0; i < 3; ++i) {
    int f = t + i * 512;                     // 0..1535
    int col = f >> 5;                        // 0..47
    int kg = (f & 31) << 3;                  // 0..248
    int kk = kg >> 5, ko = kg & 31;
    *(u16x8*)&Bh[kk][col][ko] = *(const u16x8*)(Whi + (size_t)(cy * 48 + col) * 256 + kg);
    *(u16x8*)&Bl[kk][col][ko] = *(const u16x8*)(Wlo + (size_t)(cy * 48 + col) * 256 + kg);
  }
  __syncthreads();

  f32x4 acc[2][3] = {};
  f32x4 qs[2][2][2];                         // [parity][m][half]

  auto LQ = [&](int kk, int s) {
    #pragma unroll
    for (int m = 0; m < 2; ++m) {
      const float* p = query + (size_t)(row0 + m * 16 + l15) * CDIM + kk * 32 + l4 * 8;
      qs[s][m][0] = *(const f32x4*)p;
      qs[s][m][1] = *(const f32x4*)(p + 4);
    }
  };

  LQ(0, 0);
  LQ(1, 1);
  #pragma unroll
  for (int kk = 0; kk < 8; ++kk) {
    const int s = kk & 1;
    bf16x8 ah[2], al[2];
    #pragma unroll
    for (int m = 0; m < 2; ++m) {
      #pragma unroll
      for (int i = 0; i < 4; ++i) {
        float v0 = qs[s][m][0][i], v1 = qs[s][m][1][i];
        unsigned short h0 = hwbf(v0), h1 = hwbf(v1);
        ah[m][i]     = (short)h0;
        ah[m][4 + i] = (short)h1;
        al[m][i]     = (short)hwbf(v0 - bf2f(h0));
        al[m][4 + i] = (short)hwbf(v1 - bf2f(h1));
      }
    }
    if (kk < 6) LQ(kk + 2, s);
    #pragma unroll
    for (int c = 0; c < 3; ++c) {
      bf16x8 bh = *(const bf16x8*)&Bh[kk][c * 16 + l15][l4 * 8];
      bf16x8 bl = *(const bf16x8*)&Bl[kk][c * 16 + l15][l4 * 8];
      acc[0][c] = __builtin_amdgcn_mfma_f32_16x16x32_bf16(ah[0], bh, acc[0][c], 0, 0, 0);
      acc[0][c] = __builtin_amdgcn_mfma_f32_16x16x32_bf16(al[0], bh, acc[0][c], 0, 0, 0);
      acc[0][c] = __builtin_amdgcn_mfma_f32_16x16x32_bf16(ah[0], bl, acc[0][c], 0, 0, 0);
      acc[1][c] = __builtin_amdgcn_mfma_f32_16x16x32_bf16(ah[1], bh, acc[1][c], 0, 0, 0);
      acc[1][c] = __builtin_amdgcn_mfma_f32_16x16x32_bf16(al[1], bh, acc[1][c], 0, 0, 0);
      acc[1][c] = __builtin_amdgcn_mfma_f32_16x16x32_bf16(ah[1], bl, acc[1][c], 0, 0, 0);
    }
  }

  #pragma unroll
  for (int c = 0; c < 3; ++c) {
    const int gct = cy * 3 + c;             // global col-tile 0..5
    const int col = gct * 16 + l15;         // 0..95
    const float bias = (gct < 4) ? boff[col] : battn[col - 64];
    #pragma unroll
    for (int m = 0; m < 2; ++m) {
      #pragma unroll
      for (int r = 0; r < 4; ++r) {
        const int row = row0 + m * 16 + l4 * 4 + r;
        float v = acc[m][c][r] + bias;
        if (gct < 4) {
          float off = tanhf(v) * 0.5f;
          float rp = refp[(size_t)row * 2 + (col & 1)];
          loc[(size_t)row * 64 + col] = (rp + off) * 128.0f - 0.5f;
        } else {
          int j = col - 64;
          float m1 = fmaxf(v, __shfl_xor(v, 1));
          float mm = fmaxf(m1, __shfl_xor(m1, 2));
          float e = expf(v - mm);
          float s2 = e;
          s2 += __shfl_xor(s2, 1);
          s2 += __shfl_xor(s2, 2);
          attnw[((size_t)(j >> 2) * Mrows + row) * 4 + (j & 3)] = e / s2;
        }
      }
    }
  }
}

// ---------------------------------------------------------------------------
// Bilinear sampling + attn-weighted sum, packed-math inner loop (R19).
// RAW-RESHAPE QUIRK: output (b,n,h,p) uses loc of (n_l = h*2048 + (n>>3),
// h_l = n&7, p) on map (b,h). grid (8, M/64); blockIdx.x = h (head-per-XCD
// L2 locality). 4 consecutive lanes gather one 64B corner cooperatively.
// ---------------------------------------------------------------------------
__global__ __launch_bounds__(256) void sample_k(
    const unsigned short* __restrict__ vmap, const float* __restrict__ loc,
    const float* __restrict__ attnw, unsigned short* __restrict__ mid, int Mrows) {
  const int t = threadIdx.x;
  const int h = blockIdx.x;            // 0..7
  const int r = t >> 2;                // 0..63
  const int sub = t & 3;               // channel quad (8 channels, 16B)
  const int row = blockIdx.y * 64 + r;
  const int b = row >> 14, n = row & (HW - 1);
  const int n_l = h * 2048 + (n >> 3);
  const int h_l = n & 7;
  const float* lp = loc + (size_t)(b * HW + n_l) * 64 + h_l * 8;
  const f32x4 aq = *(const f32x4*)(attnw + ((size_t)h * Mrows + row) * 4);
  const unsigned short* map = vmap + (size_t)(b * NH + h) * HW * DH + sub * 8;

  f32x4 l01 = *(const f32x4*)(lp);      // p0.x p0.y p1.x p1.y
  f32x4 l23 = *(const f32x4*)(lp + 4);  // p2.x p2.y p3.x p3.y

  f32x2 acc2[4];
  #pragma unroll
  for (int j = 0; j < 4; ++j) acc2[j] = (f32x2){0.f, 0.f};

  #pragma unroll
  for (int p = 0; p < NPTS; ++p) {
    float ix = (p < 2) ? l01[(p & 1) * 2] : l23[(p & 1) * 2];
    float iy = (p < 2) ? l01[(p & 1) * 2 + 1] : l23[(p & 1) * 2 + 1];
    float aw = aq[p];
    float xf = floorf(ix), yf = floorf(iy);
    float tx = ix - xf, ty = iy - yf;
    int x0 = (int)xf, y0 = (int)yf;
    float w00 = (1.f - tx) * (1.f - ty) * aw, w01 = tx * (1.f - ty) * aw;
    float w10 = (1.f - tx) * ty * aw,         w11 = tx * ty * aw;
    int xs[4] = {x0, x0 + 1, x0, x0 + 1};
    int ys[4] = {y0, y0, y0 + 1, y0 + 1};
    float wg[4] = {w00, w01, w10, w11};
    #pragma unroll
    for (int cn = 0; cn < 4; ++cn) {
      int xx = xs[cn], yy = ys[cn];
      if ((unsigned)xx < 128u && (unsigned)yy < 128u) {
        uint4 uv = *(const uint4*)(map + (((size_t)yy << 7) + xx) * DH);
        float wgt = wg[cn];
        f32x2 w2 = {wgt, wgt};
        unsigned us[4] = {uv.x, uv.y, uv.z, uv.w};
        #pragma unroll
        for (int j = 0; j < 4; ++j) {
          f32x2 val;
          val[0] = __uint_as_float(us[j] << 16);          // channel 2j
          val[1] = __uint_as_float(us[j] & 0xffff0000u);  // channel 2j+1
          acc2[j] += w2 * val;                            // v_pk_fma_f32
        }
      }
    }
  }
  u16x8 o;
  #pragma unroll
  for (int j = 0; j < 4; ++j) {
    o[2 * j]     = f2bf(acc2[j][0]);
    o[2 * j + 1] = f2bf(acc2[j][1]);
  }
  *(u16x8*)(mid + ((size_t)h * Mrows + row) * DH + sub * 8) = o;
}

extern "C" void kernel_launch(void* const* d_in, const int* in_sizes, int n_in,
                              void* d_out, int out_size, void* d_ws, size_t ws_size,
                              hipStream_t stream) {
  const float* query = (const float*)d_in[0];
  const float* refp  = (const float*)d_in[1];
  const float* value = (const float*)d_in[2];
  const float* Wv    = (const float*)d_in[3];
  const float* bv    = (const float*)d_in[4];
  const float* Woff  = (const float*)d_in[5];
  const float* boff  = (const float*)d_in[6];
  const float* Wattn = (const float*)d_in[7];
  const float* battn = (const float*)d_in[8];
  const float* Wout  = (const float*)d_in[9];
  const float* bout  = (const float*)d_in[10];

  const int M = in_sizes[0] / CDIM;          // B*N = 65536

  char* ws = (char*)d_ws;
  unsigned short* vmap = (unsigned short*)ws;                 // M*256 bf16 = 33.5 MB
  size_t off1 = (size_t)M * CDIM * 2;
  float* loc = (float*)(ws + off1);                           // M*64 f32 = 16.8 MB
  size_t off2 = off1 + (size_t)M * 64 * 4;
  float* attnw = (float*)(ws + off2);                         // [h][M][4] f32 = 8.4 MB
  size_t off3 = off2 + (size_t)M * 32 * 4;
  unsigned short* mid = (unsigned short*)(ws + off3);         // [h][M][32] bf16 = 33.5 MB
  size_t off4 = off3 + (size_t)M * CDIM * 2;
  unsigned short* wvT = (unsigned short*)(ws + off4);         // 256x256 bf16 = 128 KB
  unsigned short* woT = wvT + CDIM * CDIM;                    // 256x256 bf16 = 128 KB
  unsigned short* Whi = woT + CDIM * CDIM;                    // 96x256 bf16 = 48 KB
  unsigned short* Wlo = Whi + 96 * CDIM;                      // 96x256 bf16 = 48 KB

  hipLaunchKernelGGL(prep_k, dim3(4, 4, 2), dim3(256), 0, stream, Wv, Wout, wvT, woT);
  hipLaunchKernelGGL(prepw_k, dim3(96), dim3(256), 0, stream, Woff, Wattn, Whi, Wlo);
  hipLaunchKernelGGL((gemm_k<false, 0, 64>), dim3(M / 64), dim3(256), 0, stream,
                     value, wvT, bv, vmap, M);
  hipLaunchKernelGGL(offattn_k, dim3((M / 256) * 2), dim3(512), 0, stream,
                     query, refp, Whi, Wlo, boff, battn, loc, attnw, M);
  hipLaunchKernelGGL(sample_k, dim3(8, M / 64), dim3(256), 0, stream,
                     vmap, loc, attnw, mid, M);
  hipLaunchKernelGGL((gemm_k<true, 1, 128>), dim3(M / 128), dim3(256), 0, stream,
                     mid, woT, bout, (float*)d_out, M);
}

// Round 21
// 130.651 us; speedup vs baseline: 1.0588x; 1.0588x over previous
//
#include <hip/hip_runtime.h>
#include <hip/hip_bf16.h>

#define DH    32          // d_head
#define NH    8
#define NPTS  4
#define CDIM  256
#define HW    16384       // H*W = 128*128
#define HDIM  128

typedef __attribute__((ext_vector_type(8))) short bf16x8;
typedef __attribute__((ext_vector_type(4))) float f32x4;
typedef __attribute__((ext_vector_type(2))) float f32x2;
typedef __attribute__((ext_vector_type(8))) unsigned short u16x8;

__device__ __forceinline__ unsigned short f2bf(float f) {
  unsigned u = __float_as_uint(f);
  u += 0x7FFFu + ((u >> 16) & 1u);          // round-to-nearest-even
  return (unsigned short)(u >> 16);
}
__device__ __forceinline__ float bf2f(unsigned short s) {
  return __uint_as_float(((unsigned)s) << 16);
}
// hardware RNE cast (pairs compile to v_cvt_pk_bf16_f32)
__device__ __forceinline__ unsigned short hwbf(float f) {
  __hip_bfloat16 h = __float2bfloat16(f);
  return __builtin_bit_cast(unsigned short, h);
}
// async global->LDS DMA, 16B per lane; lds dst must be wave-uniform
__device__ __forceinline__ void gload16(const void* g, void* l) {
  __builtin_amdgcn_global_load_lds(
      (const __attribute__((address_space(1))) void*)g,
      (__attribute__((address_space(3))) void*)l, 16, 0, 0);
}

// ---------------------------------------------------------------------------
// One-shot weight prep: f32 [k][col] (256x256) -> bf16 transposed [col][k].
// ---------------------------------------------------------------------------
__global__ __launch_bounds__(256) void prep_k(
    const float* __restrict__ W0, const float* __restrict__ W1,
    unsigned short* __restrict__ T0, unsigned short* __restrict__ T1) {
  __shared__ unsigned short tile[64][68];
  const float* W = blockIdx.z ? W1 : W0;
  unsigned short* T = blockIdx.z ? T1 : T0;
  const int r0 = blockIdx.x * 64, c0 = blockIdx.y * 64;
  const int t = threadIdx.x;
  #pragma unroll
  for (int i = 0; i < 4; ++i) {
    int f = t + i * 256;                     // 1024 float4
    int r = f >> 4, c4 = (f & 15) << 2;
    float4 v = *(const float4*)(W + (size_t)(r0 + r) * CDIM + c0 + c4);
    ushort4 s;
    s.x = f2bf(v.x); s.y = f2bf(v.y); s.z = f2bf(v.z); s.w = f2bf(v.w);
    *(ushort4*)&tile[r][c4] = s;
  }
  __syncthreads();
  #pragma unroll
  for (int i = 0; i < 4; ++i) {
    int f = t + i * 256;
    int c = f >> 4, r4 = (f & 15) << 2;
    ushort4 o;
    o.x = tile[r4 + 0][c]; o.y = tile[r4 + 1][c];
    o.z = tile[r4 + 2][c]; o.w = tile[r4 + 3][c];
    *(ushort4*)(T + (size_t)(c0 + c) * CDIM + r0 + r4) = o;
  }
}

// ---------------------------------------------------------------------------
// One-shot offset/attn weight prep: split hi/lo bf16, transposed [col][k].
// ---------------------------------------------------------------------------
__global__ __launch_bounds__(256) void prepw_k(
    const float* __restrict__ Woff, const float* __restrict__ Wattn,
    unsigned short* __restrict__ Whi, unsigned short* __restrict__ Wlo) {
  const int c = blockIdx.x, k = threadIdx.x;
  float x = (c < 64) ? Woff[(size_t)k * 64 + c] : Wattn[(size_t)k * 32 + (c - 64)];
  unsigned short h = f2bf(x);
  Whi[(size_t)c * 256 + k] = h;
  Wlo[(size_t)c * 256 + k] = f2bf(x - bf2f(h));
}

// ---------------------------------------------------------------------------
// GEMM, full-width 128 x 256 tile (A read once from HBM) — R16-best.
// 4 waves: wave w owns rows (w>>1)*64, cols (w&1)*128; acc[4][8]. BK=32,
// double-buffered LDS via global_load_lds, counted-vmcnt schedule. A-f32
// XOR-swizzled (pre-swizzled global src + swizzled ds_read); bf16 A and B
// linear (bank-uniform b128 reads). Grid = M/128.
// ---------------------------------------------------------------------------
template<bool ABF16, int EPI>
__global__ __launch_bounds__(256) void gemm_k(
    const void* __restrict__ Ap, const unsigned short* __restrict__ Bt,
    const float* __restrict__ bias, void* __restrict__ Cp, int Mrows) {
  __shared__ char lds[ABF16 ? 49152 : 65536];
  char* Abase = lds;                                   // [2] A-tiles
  char* Bbase = lds + (ABF16 ? 16384 : 32768);         // [2][256col][64B]
  const int ABUF = ABF16 ? 8192 : 16384;
  const int mt = blockIdx.x;
  const int t = threadIdx.x;
  const int lane = t & 63, w = t >> 6;
  const int wr = w >> 1, wcol = w & 1;
  const int l15 = lane & 15, l4 = lane >> 4;
  const char* Ag = (const char*)Ap;

  f32x4 acc[4][8] = {};

  auto stage = [&](int kk, int s) {
    if (!ABF16) {
      const int lrow = lane >> 3;
      const int lkb = ((lane & 7) ^ lrow) << 4;        // XOR pre-swizzle
      #pragma unroll
      for (int i = 0; i < 4; ++i) {
        int chunk = w * 4 + i;
        int row = chunk * 8 + lrow;
        const char* src = Ag + ((size_t)(mt * 128 + row) * CDIM + kk * 32) * 4 + lkb;
        gload16(src, Abase + s * ABUF + chunk * 1024);
      }
    } else {
      const int lrow = lane >> 2;
      const int lkb = (lane & 3) << 4;
      #pragma unroll
      for (int i = 0; i < 2; ++i) {
        int chunk = w * 2 + i;
        int row = chunk * 16 + lrow;
        const char* src = Ag + ((size_t)kk * Mrows + mt * 128 + row) * 64 + lkb;
        gload16(src, Abase + s * ABUF + chunk * 1024);
      }
    }
    const int lcol = lane >> 2;
    const int lkb = (lane & 3) << 4;
    #pragma unroll
    for (int i = 0; i < 4; ++i) {
      int chunk = w * 4 + i;
      int col = chunk * 16 + lcol;
      const char* src = (const char*)Bt + ((size_t)col * CDIM + kk * 32) * 2 + lkb;
      gload16(src, Bbase + s * 16384 + chunk * 1024);
    }
  };

  stage(0, 0);
  #pragma unroll
  for (int kk = 0; kk < 8; ++kk) {
    const int s = kk & 1;
    if (kk < 7) {
      stage(kk + 1, s ^ 1);
      asm volatile("s_waitcnt vmcnt(%0)" :: "i"(ABF16 ? 6 : 8) : "memory");
    } else {
      asm volatile("s_waitcnt vmcnt(0)" ::: "memory");
    }
    __builtin_amdgcn_s_barrier();
    bf16x8 a[4], bb[8];
    if (!ABF16) {
      const int sw = (l15 & 7) << 4;
      #pragma unroll
      for (int m = 0; m < 4; ++m) {
        const char* arow = Abase + s * ABUF + (wr * 64 + m * 16 + l15) * 128;
        f32x4 v0 = *(const f32x4*)(arow + ((l4 * 32) ^ sw));
        f32x4 v1 = *(const f32x4*)(arow + ((l4 * 32 + 16) ^ sw));
        #pragma unroll
        for (int i = 0; i < 4; ++i) {
          a[m][i]     = (short)hwbf(v0[i]);
          a[m][4 + i] = (short)hwbf(v1[i]);
        }
      }
    } else {
      #pragma unroll
      for (int m = 0; m < 4; ++m)
        a[m] = *(const bf16x8*)(Abase + s * ABUF + (wr * 64 + m * 16 + l15) * 64 + l4 * 16);
    }
    #pragma unroll
    for (int n = 0; n < 8; ++n)
      bb[n] = *(const bf16x8*)(Bbase + s * 16384 +
                               (wcol * 128 + n * 16 + l15) * 64 + l4 * 16);
    #pragma unroll
    for (int m = 0; m < 4; ++m)
      #pragma unroll
      for (int n = 0; n < 8; ++n)
        acc[m][n] = __builtin_amdgcn_mfma_f32_16x16x32_bf16(a[m], bb[n], acc[m][n], 0, 0, 0);
    asm volatile("s_waitcnt lgkmcnt(0)" ::: "memory");
    __builtin_amdgcn_s_barrier();        // buffer-overwrite protection
  }

  #pragma unroll
  for (int m = 0; m < 4; ++m) {
    #pragma unroll
    for (int n = 0; n < 8; ++n) {
      #pragma unroll
      for (int r = 0; r < 4; ++r) {
        int R = mt * 128 + wr * 64 + m * 16 + l4 * 4 + r;
        int Cg = wcol * 128 + n * 16 + l15;
        float v = acc[m][n][r] + bias[Cg];
        if (EPI == 0) {
          int b2 = R >> 14, ntok = R & (HW - 1);
          int h = Cg >> 5, c = Cg & 31;
          ((unsigned short*)Cp)[((size_t)(b2 * NH + h) * HW + ntok) * DH + c] = hwbf(v);
        } else {
          ((float*)Cp)[(size_t)R * CDIM + Cg] = v;
        }
      }
    }
  }
}

// ---------------------------------------------------------------------------
// Offsets + attention (R16-best): barrier-free K-loop + 2-deep A prefetch.
// Weights (hi/lo bf16, [col][k]) in LDS once (54KB); A (query f32) read
// straight from global into fragments, split hi/lo in-register.
// 1-D grid, cy = bid&1 (col-half pairs dispatch-adjacent -> L2 pairing).
// Block: 512 thr (8 waves x 32 rows).
// ---------------------------------------------------------------------------
__global__ __launch_bounds__(512) void offattn_k(
    const float* __restrict__ query, const float* __restrict__ refp,
    const unsigned short* __restrict__ Whi, const unsigned short* __restrict__ Wlo,
    const float* __restrict__ boff, const float* __restrict__ battn,
    float* __restrict__ loc, float* __restrict__ attnw, int Mrows) {
  __shared__ unsigned short Bh[8][48][36], Bl[8][48][36];   // 54 KB
  const int t = threadIdx.x;
  const int lane = t & 63, w = t >> 6;
  const int l15 = lane & 15, l4 = lane >> 4;
  const int cy = blockIdx.x & 1;             // col-half: cols cy*48..cy*48+47
  const int row0 = (blockIdx.x >> 1) * 256 + w * 32;

  #pragma unroll
  for (int i = 0; i < 3; ++i) {
    int f = t + i * 512;                     // 0..1535
    int col = f >> 5;                        // 0..47
    int kg = (f & 31) << 3;                  // 0..248
    int kk = kg >> 5, ko = kg & 31;
    *(u16x8*)&Bh[kk][col][ko] = *(const u16x8*)(Whi + (size_t)(cy * 48 + col) * 256 + kg);
    *(u16x8*)&Bl[kk][col][ko] = *(const u16x8*)(Wlo + (size_t)(cy * 48 + col) * 256 + kg);
  }
  __syncthreads();

  f32x4 acc[2][3] = {};
  f32x4 qs[2][2][2];                         // [parity][m][half]

  auto LQ = [&](int kk, int s) {
    #pragma unroll
    for (int m = 0; m < 2; ++m) {
      const float* p = query + (size_t)(row0 + m * 16 + l15) * CDIM + kk * 32 + l4 * 8;
      qs[s][m][0] = *(const f32x4*)p;
      qs[s][m][1] = *(const f32x4*)(p + 4);
    }
  };

  LQ(0, 0);
  LQ(1, 1);
  #pragma unroll
  for (int kk = 0; kk < 8; ++kk) {
    const int s = kk & 1;
    bf16x8 ah[2], al[2];
    #pragma unroll
    for (int m = 0; m < 2; ++m) {
      #pragma unroll
      for (int i = 0; i < 4; ++i) {
        float v0 = qs[s][m][0][i], v1 = qs[s][m][1][i];
        unsigned short h0 = hwbf(v0), h1 = hwbf(v1);
        ah[m][i]     = (short)h0;
        ah[m][4 + i] = (short)h1;
        al[m][i]     = (short)hwbf(v0 - bf2f(h0));
        al[m][4 + i] = (short)hwbf(v1 - bf2f(h1));
      }
    }
    if (kk < 6) LQ(kk + 2, s);
    #pragma unroll
    for (int c = 0; c < 3; ++c) {
      bf16x8 bh = *(const bf16x8*)&Bh[kk][c * 16 + l15][l4 * 8];
      bf16x8 bl = *(const bf16x8*)&Bl[kk][c * 16 + l15][l4 * 8];
      acc[0][c] = __builtin_amdgcn_mfma_f32_16x16x32_bf16(ah[0], bh, acc[0][c], 0, 0, 0);
      acc[0][c] = __builtin_amdgcn_mfma_f32_16x16x32_bf16(al[0], bh, acc[0][c], 0, 0, 0);
      acc[0][c] = __builtin_amdgcn_mfma_f32_16x16x32_bf16(ah[0], bl, acc[0][c], 0, 0, 0);
      acc[1][c] = __builtin_amdgcn_mfma_f32_16x16x32_bf16(ah[1], bh, acc[1][c], 0, 0, 0);
      acc[1][c] = __builtin_amdgcn_mfma_f32_16x16x32_bf16(al[1], bh, acc[1][c], 0, 0, 0);
      acc[1][c] = __builtin_amdgcn_mfma_f32_16x16x32_bf16(ah[1], bl, acc[1][c], 0, 0, 0);
    }
  }

  #pragma unroll
  for (int c = 0; c < 3; ++c) {
    const int gct = cy * 3 + c;             // global col-tile 0..5
    const int col = gct * 16 + l15;         // 0..95
    const float bias = (gct < 4) ? boff[col] : battn[col - 64];
    #pragma unroll
    for (int m = 0; m < 2; ++m) {
      #pragma unroll
      for (int r = 0; r < 4; ++r) {
        const int row = row0 + m * 16 + l4 * 4 + r;
        float v = acc[m][c][r] + bias;
        if (gct < 4) {
          float off = tanhf(v) * 0.5f;
          float rp = refp[(size_t)row * 2 + (col & 1)];
          loc[(size_t)row * 64 + col] = (rp + off) * 128.0f - 0.5f;
        } else {
          int j = col - 64;
          float m1 = fmaxf(v, __shfl_xor(v, 1));
          float mm = fmaxf(m1, __shfl_xor(m1, 2));
          float e = expf(v - mm);
          float s2 = e;
          s2 += __shfl_xor(s2, 1);
          s2 += __shfl_xor(s2, 2);
          attnw[((size_t)(j >> 2) * Mrows + row) * 4 + (j & 3)] = e / s2;
        }
      }
    }
  }
}

// ---------------------------------------------------------------------------
// Bilinear sampling + attn-weighted sum — BRANCHLESS gathers for MLP depth.
// All 16 corner (addr, weight) pairs computed first (coords clamped to
// [0,127], weight zeroed when OOB — identical semantics to clip+mask), then
// 16 unconditional uint4 loads issued back-to-back (16-deep load window,
// no exec-mask fences), then packed-math accumulation.
// RAW-RESHAPE QUIRK: output (b,n,h,p) uses loc of (n_l = h*2048 + (n>>3),
// h_l = n&7, p) on map (b,h). grid (8, M/64); blockIdx.x = h (head-per-XCD
// L2 locality). 4 consecutive lanes gather one 64B corner cooperatively.
// ---------------------------------------------------------------------------
__global__ __launch_bounds__(256) void sample_k(
    const unsigned short* __restrict__ vmap, const float* __restrict__ loc,
    const float* __restrict__ attnw, unsigned short* __restrict__ mid, int Mrows) {
  const int t = threadIdx.x;
  const int h = blockIdx.x;            // 0..7
  const int r = t >> 2;                // 0..63
  const int sub = t & 3;               // channel quad (8 channels, 16B)
  const int row = blockIdx.y * 64 + r;
  const int b = row >> 14, n = row & (HW - 1);
  const int n_l = h * 2048 + (n >> 3);
  const int h_l = n & 7;
  const float* lp = loc + (size_t)(b * HW + n_l) * 64 + h_l * 8;
  const f32x4 aq = *(const f32x4*)(attnw + ((size_t)h * Mrows + row) * 4);
  const unsigned short* map = vmap + (size_t)(b * NH + h) * HW * DH + sub * 8;

  f32x4 l01 = *(const f32x4*)(lp);      // p0.x p0.y p1.x p1.y
  f32x4 l23 = *(const f32x4*)(lp + 4);  // p2.x p2.y p3.x p3.y

  // phase 1: all 16 (offset, weight) pairs, branchless
  int offs[16];
  float wgts[16];
  #pragma unroll
  for (int p = 0; p < NPTS; ++p) {
    float ix = (p < 2) ? l01[(p & 1) * 2] : l23[(p & 1) * 2];
    float iy = (p < 2) ? l01[(p & 1) * 2 + 1] : l23[(p & 1) * 2 + 1];
    float aw = aq[p];
    float xf = floorf(ix), yf = floorf(iy);
    float tx = ix - xf, ty = iy - yf;
    int x0 = (int)xf, y0 = (int)yf;
    float wgt4[4] = {(1.f - tx) * (1.f - ty) * aw, tx * (1.f - ty) * aw,
                     (1.f - tx) * ty * aw,         tx * ty * aw};
    #pragma unroll
    for (int cn = 0; cn < 4; ++cn) {
      int xx = x0 + (cn & 1), yy = y0 + (cn >> 1);
      float valid = (((unsigned)xx < 128u) & ((unsigned)yy < 128u)) ? 1.f : 0.f;
      int xc = min(max(xx, 0), 127), yc = min(max(yy, 0), 127);
      offs[p * 4 + cn] = ((yc << 7) + xc) * DH;
      wgts[p * 4 + cn] = wgt4[cn] * valid;
    }
  }
  // phase 2: 16 unconditional loads (independent -> deep MLP)
  uint4 vals[16];
  #pragma unroll
  for (int g = 0; g < 16; ++g)
    vals[g] = *(const uint4*)(map + offs[g]);
  // phase 3: packed accumulation
  f32x2 acc2[4];
  #pragma unroll
  for (int j = 0; j < 4; ++j) acc2[j] = (f32x2){0.f, 0.f};
  #pragma unroll
  for (int g = 0; g < 16; ++g) {
    float wgt = wgts[g];
    f32x2 w2 = {wgt, wgt};
    unsigned us[4] = {vals[g].x, vals[g].y, vals[g].z, vals[g].w};
    #pragma unroll
    for (int j = 0; j < 4; ++j) {
      f32x2 val;
      val[0] = __uint_as_float(us[j] << 16);          // channel 2j
      val[1] = __uint_as_float(us[j] & 0xffff0000u);  // channel 2j+1
      acc2[j] += w2 * val;                            // v_pk_fma_f32
    }
  }
  u16x8 o;
  #pragma unroll
  for (int j = 0; j < 4; ++j) {
    o[2 * j]     = f2bf(acc2[j][0]);
    o[2 * j + 1] = f2bf(acc2[j][1]);
  }
  *(u16x8*)(mid + ((size_t)h * Mrows + row) * DH + sub * 8) = o;
}

extern "C" void kernel_launch(void* const* d_in, const int* in_sizes, int n_in,
                              void* d_out, int out_size, void* d_ws, size_t ws_size,
                              hipStream_t stream) {
  const float* query = (const float*)d_in[0];
  const float* refp  = (const float*)d_in[1];
  const float* value = (const float*)d_in[2];
  const float* Wv    = (const float*)d_in[3];
  const float* bv    = (const float*)d_in[4];
  const float* Woff  = (const float*)d_in[5];
  const float* boff  = (const float*)d_in[6];
  const float* Wattn = (const float*)d_in[7];
  const float* battn = (const float*)d_in[8];
  const float* Wout  = (const float*)d_in[9];
  const float* bout  = (const float*)d_in[10];

  const int M = in_sizes[0] / CDIM;          // B*N = 65536

  char* ws = (char*)d_ws;
  unsigned short* vmap = (unsigned short*)ws;                 // M*256 bf16 = 33.5 MB
  size_t off1 = (size_t)M * CDIM * 2;
  float* loc = (float*)(ws + off1);                           // M*64 f32 = 16.8 MB
  size_t off2 = off1 + (size_t)M * 64 * 4;
  float* attnw = (float*)(ws + off2);                         // [h][M][4] f32 = 8.4 MB
  size_t off3 = off2 + (size_t)M * 32 * 4;
  unsigned short* mid = (unsigned short*)(ws + off3);         // [h][M][32] bf16 = 33.5 MB
  size_t off4 = off3 + (size_t)M * CDIM * 2;
  unsigned short* wvT = (unsigned short*)(ws + off4);         // 256x256 bf16 = 128 KB
  unsigned short* woT = wvT + CDIM * CDIM;                    // 256x256 bf16 = 128 KB
  unsigned short* Whi = woT + CDIM * CDIM;                    // 96x256 bf16 = 48 KB
  unsigned short* Wlo = Whi + 96 * CDIM;                      // 96x256 bf16 = 48 KB

  hipLaunchKernelGGL(prep_k, dim3(4, 4, 2), dim3(256), 0, stream, Wv, Wout, wvT, woT);
  hipLaunchKernelGGL(prepw_k, dim3(96), dim3(256), 0, stream, Woff, Wattn, Whi, Wlo);
  hipLaunchKernelGGL((gemm_k<false, 0>), dim3(M / 128), dim3(256), 0, stream,
                     value, wvT, bv, vmap, M);
  hipLaunchKernelGGL(offattn_k, dim3((M / 256) * 2), dim3(512), 0, stream,
                     query, refp, Whi, Wlo, boff, battn, loc, attnw, M);
  hipLaunchKernelGGL(sample_k, dim3(8, M / 64), dim3(256), 0, stream,
                     vmap, loc, attnw, mid, M);
  hipLaunchKernelGGL((gemm_k<true, 1>), dim3(M / 128), dim3(256), 0, stream,
                     mid, woT, bout, (float*)d_out, M);
}